// Round 8
// baseline (390.617 us; speedup 1.0000x reference)
//
#include <hip/hip_runtime.h>

#define N_NODES 100000
#define N_EDGES 1600000
#define TOTE    (N_EDGES + N_NODES)
#define NEG     0.2f
#define NB      ((N_NODES + 255) >> 8)   // 391 buckets of 256 nodes

typedef __attribute__((ext_vector_type(8))) short bf16x8;
typedef __attribute__((ext_vector_type(4))) float floatx4;

// bf16 helpers (RTNE)
__device__ __forceinline__ unsigned short f2bf(float f) {
  unsigned int u = __float_as_uint(f);
  u += 0x7fffu + ((u >> 16) & 1u);
  return (unsigned short)(u >> 16);
}
__device__ __forceinline__ float bf_lo(unsigned int r) { return __uint_as_float(r << 16); }
__device__ __forceinline__ float bf_hi(unsigned int r) { return __uint_as_float(r & 0xffff0000u); }

// ====================== binned CSR build ======================
__global__ __launch_bounds__(256) void k_zero_bcnt(int* __restrict__ bucketCnt, int* __restrict__ degHist) {
  for (int i = threadIdx.x; i < NB * 16; i += 256) bucketCnt[i] = 0;
  for (int i = threadIdx.x; i < 64 * 16; i += 256) degHist[i] = 0;
}

__global__ __launch_bounds__(256) void k_bucket_hist(const int* __restrict__ ei, int* __restrict__ bucketCnt) {
  __shared__ int h[NB];
  int t = threadIdx.x;
  for (int b = t; b < NB; b += 256) h[b] = 0;
  __syncthreads();
#pragma unroll
  for (int j = 0; j < 16; ++j) {
    int idx = blockIdx.x * 4096 + j * 256 + t;
    if (idx < N_EDGES) atomicAdd(&h[ei[N_EDGES + idx] >> 8], 1);
  }
  __syncthreads();
  for (int b = t; b < NB; b += 256) { int v = h[b]; if (v) atomicAdd(&bucketCnt[b * 16], v); }
}

__global__ __launch_bounds__(512) void k_bin_scan(const int* __restrict__ bucketCnt,
                                                  int* __restrict__ binOffs, int* __restrict__ binCursor) {
  __shared__ int sc[512];
  int t = threadIdx.x;
  int v = (t < NB) ? bucketCnt[t * 16] : 0;
  sc[t] = v; __syncthreads();
  for (int off = 1; off < 512; off <<= 1) {
    int x = (t >= off) ? sc[t - off] : 0;
    __syncthreads();
    sc[t] += x;
    __syncthreads();
  }
  int excl = sc[t] - v;
  if (t <= NB) binOffs[t] = excl;
  if (t < NB) binCursor[t * 16] = excl;
}

__global__ __launch_bounds__(256) void k_binA(const int* __restrict__ ei, int* __restrict__ binCursor,
                                              unsigned int* __restrict__ binned) {
  __shared__ int hist[NB];
  __shared__ int cur[NB];
  int t = threadIdx.x;
  for (int b = t; b < NB; b += 256) hist[b] = 0;
  __syncthreads();
  unsigned int pk[16]; int bk[16];
#pragma unroll
  for (int j = 0; j < 16; ++j) {
    int idx = blockIdx.x * 4096 + j * 256 + t;
    if (idx < N_EDGES) {
      int s = ei[idx], d = ei[N_EDGES + idx];
      bk[j] = d >> 8;
      pk[j] = ((unsigned int)s << 8) | (unsigned int)(d & 255);
      atomicAdd(&hist[bk[j]], 1);
    } else bk[j] = -1;
  }
  __syncthreads();
  for (int b = t; b < NB; b += 256) {
    int h = hist[b];
    if (h) cur[b] = atomicAdd(&binCursor[b * 16], h);
  }
  __syncthreads();
#pragma unroll
  for (int j = 0; j < 16; ++j) {
    if (bk[j] >= 0) {
      int pos = atomicAdd(&cur[bk[j]], 1);
      binned[pos] = pk[j];
    }
  }
}

__global__ __launch_bounds__(256) void k_binB(const unsigned int* __restrict__ binned,
                                              const int* __restrict__ binOffs,
                                              int* __restrict__ offs, int* __restrict__ srcs,
                                              int* __restrict__ degHist) {
  __shared__ int cnt[256];
  __shared__ int sc[256];
  __shared__ int cur[256];
  __shared__ int dh[64];
  int b = blockIdx.x;
  int t = threadIdx.x;
  int node0 = b << 8;
  int nNodes = min(256, N_NODES - node0);
  int e0 = binOffs[b], e1 = binOffs[b + 1];
  int base = e0 + node0;

  cnt[t] = 0;
  if (t < 64) dh[t] = 0;
  __syncthreads();
  for (int i = e0 + t; i < e1; i += 256) atomicAdd(&cnt[binned[i] & 255u], 1);
  __syncthreads();

  int v = (t < nNodes) ? cnt[t] + 1 : 0;   // +1 self-loop
  sc[t] = v; __syncthreads();
  for (int off = 1; off < 256; off <<= 1) {
    int x = (t >= off) ? sc[t - off] : 0;
    __syncthreads();
    sc[t] += x;
    __syncthreads();
  }
  int excl = sc[t] - v;
  if (t < nNodes) {
    offs[node0 + t] = base + excl;
    srcs[base + excl] = node0 + t;
    atomicAdd(&dh[min(v, 63)], 1);   // degree histogram (deg = v)
  }
  cur[t] = excl + 1;
  __syncthreads();
  if (t < 64) { int x = dh[t]; if (x) atomicAdd(&degHist[t * 16], x); }

  for (int i = e0 + t; i < e1; i += 256) {
    unsigned int e = binned[i];
    int j = (int)(e & 255u);
    int s = (int)(e >> 8);
    int p = atomicAdd(&cur[j], 1);
    srcs[base + p] = s;
  }
  if (b == 0 && t == 0) offs[N_NODES] = TOTE;
}

// exclusive scan of 64 degree bins -> cursors
__global__ void k_pscan(const int* __restrict__ degHist, int* __restrict__ permCur) {
  if (threadIdx.x == 0 && blockIdx.x == 0) {
    int run = 0;
    for (int i = 0; i < 64; ++i) { int v = degHist[i * 16]; permCur[i * 16] = run; run += v; }
  }
}

// scatter nodes into degree-sorted order; also emit permuted beg/end
__global__ __launch_bounds__(256) void k_pscat(const int* __restrict__ offs, int* __restrict__ permCur,
                                               int* __restrict__ permDst, int* __restrict__ begP,
                                               int* __restrict__ endP) {
  __shared__ int hist[64];
  __shared__ int cur[64];
  int t = threadIdx.x;
  if (t < 64) hist[t] = 0;
  __syncthreads();
  int node = blockIdx.x * 256 + t;
  int beg = 0, end = 0, bin = -1;
  if (node < N_NODES) {
    beg = offs[node];
    end = offs[node + 1];
    bin = min(end - beg, 63);
    atomicAdd(&hist[bin], 1);
  }
  __syncthreads();
  if (t < 64) { int h = hist[t]; if (h) cur[t] = atomicAdd(&permCur[t * 16], h); }
  __syncthreads();
  if (bin >= 0) {
    int pos = atomicAdd(&cur[bin], 1);
    permDst[pos] = node;
    begP[pos] = beg;
    endP[pos] = end;
  }
}

// ====== W prep: fp32 W[k][n] -> frag-ready bf16 hi/lo streams; block16: WlT[c][k] ======
__global__ __launch_bounds__(256) void k_wprep(const float* __restrict__ W1, const float* __restrict__ W2,
                                               const float* __restrict__ Wl,
                                               unsigned short* __restrict__ B1hi, unsigned short* __restrict__ B1lo,
                                               unsigned short* __restrict__ B2hi, unsigned short* __restrict__ B2lo,
                                               float* __restrict__ WlT) {
  int b = blockIdx.x;                       // 0..16
  int t = threadIdx.x;
  if (b == 16) {
    for (int i = t; i < 1280; i += 256) {
      int c = i >> 7, k = i & 127;
      WlT[i] = Wl[k * 10 + c];
    }
    return;
  }
  const float* W = (b < 8) ? W1 : W2;
  unsigned short* Bh = (b < 8) ? B1hi : B2hi;
  unsigned short* Bl = (b < 8) ? B1lo : B2lo;
  int ntile = b & 7;
  int kq = t >> 6, lane = t & 63;
  int q = lane >> 4, m = lane & 15;
  int n = ntile * 16 + m;
  union { unsigned short us[8]; uint4 u4; } hi, lo;
#pragma unroll
  for (int j = 0; j < 8; ++j) {
    int k = kq * 32 + q * 8 + j;
    float w = W[(size_t)k * 128 + n];
    unsigned int u = __float_as_uint(w);
    hi.us[j] = (unsigned short)(u >> 16);
    float res = w - __uint_as_float(u & 0xffff0000u);
    lo.us[j] = f2bf(res);
  }
  size_t fo = ((size_t)(ntile * 4 + kq) * 64 + lane) * 8;
  *reinterpret_cast<uint4*>(Bh + fo) = hi.u4;
  *reinterpret_cast<uint4*>(Bl + fo) = lo.u4;
}

// ====== MFMA GEMM [M,128]@[128,128] + fused alpha dots + block max; bf16 C out ======
template <bool SPLIT>
__global__ __launch_bounds__(256) void k_gemm_mfma(const void* __restrict__ Aptr,
                                                   const unsigned short* __restrict__ Bhi,
                                                   const unsigned short* __restrict__ Blo,
                                                   unsigned short* __restrict__ Cb,
                                                   const float* __restrict__ avS, const float* __restrict__ avD,
                                                   float* __restrict__ aS, float* __restrict__ aD,
                                                   float* __restrict__ slotS, float* __restrict__ slotD) {
  __shared__ unsigned short sC[128 * 136];
  __shared__ float redS[128 * 2], redD[128 * 2];
  __shared__ float mS[128], mD[128];
  int t = threadIdx.x;
  int w = t >> 6, lane = t & 63;
  int q = lane >> 4, m = lane & 15;
  int wr = (w >> 1) * 64, wc = (w & 1) * 64;
  int rbase = blockIdx.x * 128;

  floatx4 acc[4][4];
#pragma unroll
  for (int mt = 0; mt < 4; ++mt)
#pragma unroll
    for (int nt = 0; nt < 4; ++nt) acc[mt][nt] = (floatx4){0.f, 0.f, 0.f, 0.f};

#pragma unroll
  for (int k0 = 0; k0 < 4; ++k0) {
    bf16x8 Bh[4], Bl[4], Ah[4], Al[4];
#pragma unroll
    for (int nt = 0; nt < 4; ++nt) {
      int ntg = (w & 1) * 4 + nt;
      size_t fo = ((size_t)(ntg * 4 + k0) * 64 + lane) * 8;
      Bh[nt] = *reinterpret_cast<const bf16x8*>(Bhi + fo);
      Bl[nt] = *reinterpret_cast<const bf16x8*>(Blo + fo);
    }
#pragma unroll
    for (int mt = 0; mt < 4; ++mt) {
      int row = rbase + wr + mt * 16 + m;
      row = min(row, N_NODES - 1);
      if constexpr (SPLIT) {
        const float* ap = (const float*)Aptr + (size_t)row * 128 + k0 * 32 + q * 8;
        float4 v0 = *reinterpret_cast<const float4*>(ap);
        float4 v1 = *reinterpret_cast<const float4*>(ap + 4);
        float av[8] = {v0.x, v0.y, v0.z, v0.w, v1.x, v1.y, v1.z, v1.w};
        union { unsigned short us[8]; bf16x8 v; } uh, ul;
#pragma unroll
        for (int j = 0; j < 8; ++j) {
          unsigned int u = __float_as_uint(av[j]);
          uh.us[j] = (unsigned short)(u >> 16);
          float res = av[j] - __uint_as_float(u & 0xffff0000u);
          ul.us[j] = f2bf(res);
        }
        Ah[mt] = uh.v; Al[mt] = ul.v;
      } else {
        const unsigned short* ap = (const unsigned short*)Aptr + (size_t)row * 128 + k0 * 32 + q * 8;
        Ah[mt] = *reinterpret_cast<const bf16x8*>(ap);
      }
    }
#pragma unroll
    for (int mt = 0; mt < 4; ++mt)
#pragma unroll
      for (int nt = 0; nt < 4; ++nt) {
        acc[mt][nt] = __builtin_amdgcn_mfma_f32_16x16x32_bf16(Ah[mt], Bh[nt], acc[mt][nt], 0, 0, 0);
        acc[mt][nt] = __builtin_amdgcn_mfma_f32_16x16x32_bf16(Ah[mt], Bl[nt], acc[mt][nt], 0, 0, 0);
        if constexpr (SPLIT)
          acc[mt][nt] = __builtin_amdgcn_mfma_f32_16x16x32_bf16(Al[mt], Bh[nt], acc[mt][nt], 0, 0, 0);
      }
  }

  // ---- fused alpha dots ----
  float avs[4], avd[4];
#pragma unroll
  for (int nt = 0; nt < 4; ++nt) {
    int c = wc + nt * 16 + m;
    avs[nt] = avS[c];
    avd[nt] = avD[c];
  }
#pragma unroll
  for (int mt = 0; mt < 4; ++mt)
#pragma unroll
    for (int r = 0; r < 4; ++r) {
      float ps = 0.f, pd = 0.f;
#pragma unroll
      for (int nt = 0; nt < 4; ++nt) {
        float cv = acc[mt][nt][r];
        ps += cv * avs[nt];
        pd += cv * avd[nt];
      }
      ps += __shfl_xor(ps, 1); pd += __shfl_xor(pd, 1);
      ps += __shfl_xor(ps, 2); pd += __shfl_xor(pd, 2);
      ps += __shfl_xor(ps, 4); pd += __shfl_xor(pd, 4);
      ps += __shfl_xor(ps, 8); pd += __shfl_xor(pd, 8);
      if (m == 0) {
        int rl = wr + mt * 16 + q * 4 + r;
        redS[rl * 2 + (w & 1)] = ps;
        redD[rl * 2 + (w & 1)] = pd;
      }
    }

  // ---- C -> LDS (bf16) ----
#pragma unroll
  for (int mt = 0; mt < 4; ++mt)
#pragma unroll
    for (int nt = 0; nt < 4; ++nt)
#pragma unroll
      for (int r = 0; r < 4; ++r) {
        int rl = wr + mt * 16 + q * 4 + r;
        int cl = wc + nt * 16 + m;
        sC[rl * 136 + cl] = f2bf(acc[mt][nt][r]);
      }
  __syncthreads();

#pragma unroll
  for (int i = 0; i < 8; ++i) {
    int idx = i * 256 + t;
    int rl = idx >> 4, kk = idx & 15;
    int gr = rbase + rl;
    if (gr < N_NODES)
      *reinterpret_cast<uint4*>(Cb + (size_t)gr * 128 + kk * 8) =
          *reinterpret_cast<const uint4*>(sC + rl * 136 + kk * 8);
  }

  if (t < 128) {
    int gr = rbase + t;
    bool ok = gr < N_NODES;
    float ps = redS[t * 2] + redS[t * 2 + 1];
    float pd = redD[t * 2] + redD[t * 2 + 1];
    if (ok) { aS[gr] = ps; aD[gr] = pd; }
    mS[t] = ok ? ps : -1e30f;
    mD[t] = ok ? pd : -1e30f;
  }
  __syncthreads();
#pragma unroll
  for (int off = 64; off > 0; off >>= 1) {
    if (t < off) { mS[t] = fmaxf(mS[t], mS[t + off]); mD[t] = fmaxf(mD[t], mD[t + off]); }
    __syncthreads();
  }
  if (t == 0) { slotS[blockIdx.x] = mS[0]; slotD[blockIdx.x] = mD[0]; }
}

__global__ __launch_bounds__(256) void k_gmax(const float* __restrict__ slotS,
                                              const float* __restrict__ slotD,
                                              int n, float* __restrict__ gMh) {
  __shared__ float sS[256], sD[256];
  int t = threadIdx.x;
  float ms = -1e30f, md = -1e30f;
  for (int i = t; i < n; i += 256) { ms = fmaxf(ms, slotS[i]); md = fmaxf(md, slotD[i]); }
  sS[t] = ms; sD[t] = md;
  __syncthreads();
#pragma unroll
  for (int off = 128; off > 0; off >>= 1) {
    if (t < off) { sS[t] = fmaxf(sS[t], sS[t + off]); sD[t] = fmaxf(sD[t], sD[t + off]); }
    __syncthreads();
  }
  if (t == 0) {
    float M = sS[0] + sD[0];
    gMh[0] = (M > 0.f) ? M : NEG * M;
  }
}

// ============ single-pass softmax + aggregation (16 lanes/dst, degree-sorted schedule) ============
#define FMA8(E, R)                                     \
  do {                                                 \
    acc[0] += (E) * bf_lo((R).x); acc[1] += (E) * bf_hi((R).x); \
    acc[2] += (E) * bf_lo((R).y); acc[3] += (E) * bf_hi((R).y); \
    acc[4] += (E) * bf_lo((R).z); acc[5] += (E) * bf_hi((R).z); \
    acc[6] += (E) * bf_lo((R).w); acc[7] += (E) * bf_hi((R).w); \
  } while (0)

template <bool FUSECLS>
__global__ __launch_bounds__(256) void k_aggregate(const unsigned short* __restrict__ hb,
                                                   const float* __restrict__ aS,
                                                   const float* __restrict__ aD,
                                                   const int* __restrict__ permDst,
                                                   const int* __restrict__ begP,
                                                   const int* __restrict__ endP,
                                                   const int* __restrict__ srcs,
                                                   const float* __restrict__ bias,
                                                   const float* __restrict__ gMh,
                                                   unsigned short* __restrict__ outb,
                                                   const float* __restrict__ WlT,
                                                   const float* __restrict__ bl,
                                                   float* __restrict__ out) {
  __shared__ float2 pairs[16 * 17];
  int t = threadIdx.x;
  int g = t >> 4;
  int l = t & 15;
  int idx = blockIdx.x * 16 + g;   // N_NODES == 16*6250 exactly
  float Mh = gMh[0];
  int dst = permDst[idx];
  int beg = begP[idx], end = endP[idx];
  float adn = aD[dst];
  float denom = 0.f;
  float acc[8];
#pragma unroll
  for (int k = 0; k < 8; ++k) acc[k] = 0.f;
  const int pbase = g * 17;

  for (int chunk = beg; chunk < end; chunk += 16) {
    int i = chunk + l;
    float ex = 0.f; int s = 0;
    if (i < end) {
      s = srcs[i];
      float e = aS[s] + adn;
      e = (e > 0.f) ? e : NEG * e;
      ex = __expf(e - Mh);   // Mh >= e always
    }
    denom += ex;
    pairs[pbase + l] = make_float2(ex, __int_as_float(s));
    // same-wave LDS RAW: DS ops in order per wave; no barrier needed
    int cnt = min(16, end - chunk);
    int j = 0;
    for (; j + 8 <= cnt; j += 8) {
      float2 pp[8]; uint4 rr[8];
#pragma unroll
      for (int u = 0; u < 8; ++u) pp[u] = pairs[pbase + j + u];
#pragma unroll
      for (int u = 0; u < 8; ++u)
        rr[u] = *reinterpret_cast<const uint4*>(hb + (size_t)__float_as_int(pp[u].y) * 128 + l * 8);
#pragma unroll
      for (int u = 0; u < 8; ++u) FMA8(pp[u].x, rr[u]);
    }
    for (; j + 4 <= cnt; j += 4) {
      float2 pp[4]; uint4 rr[4];
#pragma unroll
      for (int u = 0; u < 4; ++u) pp[u] = pairs[pbase + j + u];
#pragma unroll
      for (int u = 0; u < 4; ++u)
        rr[u] = *reinterpret_cast<const uint4*>(hb + (size_t)__float_as_int(pp[u].y) * 128 + l * 8);
#pragma unroll
      for (int u = 0; u < 4; ++u) FMA8(pp[u].x, rr[u]);
    }
    for (; j < cnt; ++j) {
      float2 pp = pairs[pbase + j];
      uint4 r = *reinterpret_cast<const uint4*>(hb + (size_t)__float_as_int(pp.y) * 128 + l * 8);
      FMA8(pp.x, r);
    }
  }
  denom += __shfl_xor(denom, 1);
  denom += __shfl_xor(denom, 2);
  denom += __shfl_xor(denom, 4);
  denom += __shfl_xor(denom, 8);
  float inv = 1.f / (denom + 1e-16f);
  float4 b0 = *reinterpret_cast<const float4*>(bias + l * 8);
  float4 b1 = *reinterpret_cast<const float4*>(bias + l * 8 + 4);
  float o0 = fmaxf(acc[0] * inv + b0.x, 0.f), o1 = fmaxf(acc[1] * inv + b0.y, 0.f);
  float o2 = fmaxf(acc[2] * inv + b0.z, 0.f), o3 = fmaxf(acc[3] * inv + b0.w, 0.f);
  float o4 = fmaxf(acc[4] * inv + b1.x, 0.f), o5 = fmaxf(acc[5] * inv + b1.y, 0.f);
  float o6 = fmaxf(acc[6] * inv + b1.z, 0.f), o7 = fmaxf(acc[7] * inv + b1.w, 0.f);

  if constexpr (!FUSECLS) {
    union { unsigned short us[8]; uint4 u4; } oo;
    oo.us[0] = f2bf(o0); oo.us[1] = f2bf(o1); oo.us[2] = f2bf(o2); oo.us[3] = f2bf(o3);
    oo.us[4] = f2bf(o4); oo.us[5] = f2bf(o5); oo.us[6] = f2bf(o6); oo.us[7] = f2bf(o7);
    *reinterpret_cast<uint4*>(outb + (size_t)dst * 128 + l * 8) = oo.u4;
  } else {
    // classifier: p[c] = sum_k h[k] * Wl[k][c]; lane holds k = l*8..l*8+7
    float p[10];
#pragma unroll
    for (int c = 0; c < 10; ++c) {
      const float4* wp = reinterpret_cast<const float4*>(WlT + c * 128 + l * 8);
      float4 w0 = wp[0], w1 = wp[1];
      p[c] = o0 * w0.x + o1 * w0.y + o2 * w0.z + o3 * w0.w
           + o4 * w1.x + o5 * w1.y + o6 * w1.z + o7 * w1.w;
    }
#pragma unroll
    for (int c = 0; c < 10; ++c) {
      p[c] += __shfl_xor(p[c], 1);
      p[c] += __shfl_xor(p[c], 2);
      p[c] += __shfl_xor(p[c], 4);
      p[c] += __shfl_xor(p[c], 8);
    }
    if (l == 0) {
      float* orow = out + (size_t)dst * 10;
      float2 bb0 = *reinterpret_cast<const float2*>(bl + 0);
      float2 bb1 = *reinterpret_cast<const float2*>(bl + 2);
      float2 bb2 = *reinterpret_cast<const float2*>(bl + 4);
      float2 bb3 = *reinterpret_cast<const float2*>(bl + 6);
      float2 bb4 = *reinterpret_cast<const float2*>(bl + 8);
      *reinterpret_cast<float2*>(orow + 0) = make_float2(p[0] + bb0.x, p[1] + bb0.y);
      *reinterpret_cast<float2*>(orow + 2) = make_float2(p[2] + bb1.x, p[3] + bb1.y);
      *reinterpret_cast<float2*>(orow + 4) = make_float2(p[4] + bb2.x, p[5] + bb2.y);
      *reinterpret_cast<float2*>(orow + 6) = make_float2(p[6] + bb3.x, p[7] + bb3.y);
      *reinterpret_cast<float2*>(orow + 8) = make_float2(p[8] + bb4.x, p[9] + bb4.y);
    }
  }
}

// ====================== launch ======================
extern "C" void kernel_launch(void* const* d_in, const int* in_sizes, int n_in,
                              void* d_out, int out_size, void* d_ws, size_t ws_size,
                              hipStream_t stream) {
  const float* x   = (const float*)d_in[0];
  const int*   ei  = (const int*)d_in[1];
  const float* W1  = (const float*)d_in[3];
  const float* as1 = (const float*)d_in[4];
  const float* ad1 = (const float*)d_in[5];
  const float* b1  = (const float*)d_in[6];
  const float* W2  = (const float*)d_in[7];
  const float* as2 = (const float*)d_in[8];
  const float* ad2 = (const float*)d_in[9];
  const float* b2  = (const float*)d_in[10];
  const float* Wl  = (const float*)d_in[11];
  const float* bl  = (const float*)d_in[12];
  float* out = (float*)d_out;

  char* p = (char*)d_ws;
  unsigned short* hb   = (unsigned short*)p; p += (size_t)N_NODES * 128 * sizeof(unsigned short);
  unsigned short* hagg = (unsigned short*)p; p += (size_t)N_NODES * 128 * sizeof(unsigned short);
  float* aS    = (float*)p; p += (size_t)N_NODES * sizeof(float);
  float* aD    = (float*)p; p += (size_t)N_NODES * sizeof(float);
  int* offs    = (int*)p;   p += (size_t)(N_NODES + 4) * sizeof(int);
  int* srcs    = (int*)p;   p += (size_t)TOTE * sizeof(int);
  int* bucketCnt = (int*)p; p += (size_t)NB * 16 * sizeof(int);
  int* binOffs   = (int*)p; p += (size_t)(NB + 4) * sizeof(int);
  int* binCursor = (int*)p; p += (size_t)NB * 16 * sizeof(int);
  int* degHist   = (int*)p; p += 64 * 16 * sizeof(int);
  int* permCur   = (int*)p; p += 64 * 16 * sizeof(int);
  int* permDst   = (int*)p; p += (size_t)N_NODES * sizeof(int);
  int* begP      = (int*)p; p += (size_t)N_NODES * sizeof(int);
  int* endP      = (int*)p; p += (size_t)N_NODES * sizeof(int);
  float* slotS = (float*)p; p += 1024 * sizeof(float);
  float* slotD = (float*)p; p += 1024 * sizeof(float);
  float* gMh = (float*)p;   p += 4 * sizeof(float);
  unsigned short* B1hi = (unsigned short*)p; p += 128 * 128 * sizeof(unsigned short);
  unsigned short* B1lo = (unsigned short*)p; p += 128 * 128 * sizeof(unsigned short);
  unsigned short* B2hi = (unsigned short*)p; p += 128 * 128 * sizeof(unsigned short);
  unsigned short* B2lo = (unsigned short*)p; p += 128 * 128 * sizeof(unsigned short);
  float* WlT = (float*)p;   p += 1280 * sizeof(float);
  unsigned int* binned = (unsigned int*)hagg;  // alias: binned dead before hagg is written

  int binBlocks = (N_EDGES + 4095) / 4096;  // 391
  int nodeBlocks = (N_NODES + 255) / 256;   // 391

  k_wprep<<<17, 256, 0, stream>>>(W1, W2, Wl, B1hi, B1lo, B2hi, B2lo, WlT);
  k_zero_bcnt<<<1, 256, 0, stream>>>(bucketCnt, degHist);
  k_bucket_hist<<<binBlocks, 256, 0, stream>>>(ei, bucketCnt);
  k_bin_scan<<<1, 512, 0, stream>>>(bucketCnt, binOffs, binCursor);
  k_binA<<<binBlocks, 256, 0, stream>>>(ei, binCursor, binned);
  k_binB<<<NB, 256, 0, stream>>>(binned, binOffs, offs, srcs, degHist);
  k_pscan<<<1, 64, 0, stream>>>(degHist, permCur);
  k_pscat<<<nodeBlocks, 256, 0, stream>>>(offs, permCur, permDst, begP, endP);

  int gemmBlocks = (N_NODES + 127) / 128;   // 782
  int aggBlocks  = N_NODES / 16;            // 6250

  // layer 1
  k_gemm_mfma<true><<<gemmBlocks, 256, 0, stream>>>(x, B1hi, B1lo, hb, as1, ad1, aS, aD, slotS, slotD);
  k_gmax<<<1, 256, 0, stream>>>(slotS, slotD, gemmBlocks, gMh);
  k_aggregate<false><<<aggBlocks, 256, 0, stream>>>(hb, aS, aD, permDst, begP, endP, srcs, b1, gMh,
                                                    hagg, nullptr, nullptr, nullptr);
  // layer 2
  k_gemm_mfma<false><<<gemmBlocks, 256, 0, stream>>>(hagg, B2hi, B2lo, hb, as2, ad2, aS, aD, slotS, slotD);
  k_gmax<<<1, 256, 0, stream>>>(slotS, slotD, gemmBlocks, gMh);
  k_aggregate<true><<<aggBlocks, 256, 0, stream>>>(hb, aS, aD, permDst, begP, endP, srcs, b2, gMh,
                                                   nullptr, WlT, bl, out);
}

// Round 9
// 389.868 us; speedup vs baseline: 1.0019x; 1.0019x over previous
//
#include <hip/hip_runtime.h>

#define N_NODES 100000
#define N_EDGES 1600000
#define TOTE    (N_EDGES + N_NODES)
#define NEG     0.2f
#define NB      ((N_NODES + 255) >> 8)   // 391 buckets of 256 nodes

typedef __attribute__((ext_vector_type(8))) short bf16x8;
typedef __attribute__((ext_vector_type(4))) float floatx4;

// bf16 helpers (RTNE)
__device__ __forceinline__ unsigned short f2bf(float f) {
  unsigned int u = __float_as_uint(f);
  u += 0x7fffu + ((u >> 16) & 1u);
  return (unsigned short)(u >> 16);
}
__device__ __forceinline__ float bf_lo(unsigned int r) { return __uint_as_float(r << 16); }
__device__ __forceinline__ float bf_hi(unsigned int r) { return __uint_as_float(r & 0xffff0000u); }

// ====================== binned CSR build ======================
__global__ __launch_bounds__(256) void k_zero_bcnt(int* __restrict__ bucketCnt) {
  for (int i = threadIdx.x; i < NB * 16; i += 256) bucketCnt[i] = 0;
}

__global__ __launch_bounds__(256) void k_bucket_hist(const int* __restrict__ ei, int* __restrict__ bucketCnt) {
  __shared__ int h[NB];
  int t = threadIdx.x;
  for (int b = t; b < NB; b += 256) h[b] = 0;
  __syncthreads();
#pragma unroll
  for (int j = 0; j < 16; ++j) {
    int idx = blockIdx.x * 4096 + j * 256 + t;
    if (idx < N_EDGES) atomicAdd(&h[ei[N_EDGES + idx] >> 8], 1);
  }
  __syncthreads();
  for (int b = t; b < NB; b += 256) { int v = h[b]; if (v) atomicAdd(&bucketCnt[b * 16], v); }
}

__global__ __launch_bounds__(512) void k_bin_scan(const int* __restrict__ bucketCnt,
                                                  int* __restrict__ binOffs, int* __restrict__ binCursor) {
  __shared__ int sc[512];
  int t = threadIdx.x;
  int v = (t < NB) ? bucketCnt[t * 16] : 0;
  sc[t] = v; __syncthreads();
  for (int off = 1; off < 512; off <<= 1) {
    int x = (t >= off) ? sc[t - off] : 0;
    __syncthreads();
    sc[t] += x;
    __syncthreads();
  }
  int excl = sc[t] - v;
  if (t <= NB) binOffs[t] = excl;
  if (t < NB) binCursor[t * 16] = excl;
}

__global__ __launch_bounds__(256) void k_binA(const int* __restrict__ ei, int* __restrict__ binCursor,
                                              unsigned int* __restrict__ binned) {
  __shared__ int hist[NB];
  __shared__ int cur[NB];
  int t = threadIdx.x;
  for (int b = t; b < NB; b += 256) hist[b] = 0;
  __syncthreads();
  unsigned int pk[16]; int bk[16];
#pragma unroll
  for (int j = 0; j < 16; ++j) {
    int idx = blockIdx.x * 4096 + j * 256 + t;
    if (idx < N_EDGES) {
      int s = ei[idx], d = ei[N_EDGES + idx];
      bk[j] = d >> 8;
      pk[j] = ((unsigned int)s << 8) | (unsigned int)(d & 255);
      atomicAdd(&hist[bk[j]], 1);
    } else bk[j] = -1;
  }
  __syncthreads();
  for (int b = t; b < NB; b += 256) {
    int h = hist[b];
    if (h) cur[b] = atomicAdd(&binCursor[b * 16], h);
  }
  __syncthreads();
#pragma unroll
  for (int j = 0; j < 16; ++j) {
    if (bk[j] >= 0) {
      int pos = atomicAdd(&cur[bk[j]], 1);
      binned[pos] = pk[j];
    }
  }
}

__global__ __launch_bounds__(256) void k_binB(const unsigned int* __restrict__ binned,
                                              const int* __restrict__ binOffs,
                                              int* __restrict__ offs, int* __restrict__ srcs) {
  __shared__ int cnt[256];
  __shared__ int sc[256];
  __shared__ int cur[256];
  int b = blockIdx.x;
  int t = threadIdx.x;
  int node0 = b << 8;
  int nNodes = min(256, N_NODES - node0);
  int e0 = binOffs[b], e1 = binOffs[b + 1];
  int base = e0 + node0;

  cnt[t] = 0; __syncthreads();
  for (int i = e0 + t; i < e1; i += 256) atomicAdd(&cnt[binned[i] & 255u], 1);
  __syncthreads();

  int v = (t < nNodes) ? cnt[t] + 1 : 0;   // +1 self-loop
  sc[t] = v; __syncthreads();
  for (int off = 1; off < 256; off <<= 1) {
    int x = (t >= off) ? sc[t - off] : 0;
    __syncthreads();
    sc[t] += x;
    __syncthreads();
  }
  int excl = sc[t] - v;
  if (t < nNodes) {
    offs[node0 + t] = base + excl;
    srcs[base + excl] = node0 + t;   // self-loop first
  }
  cur[t] = excl + 1;
  __syncthreads();

  for (int i = e0 + t; i < e1; i += 256) {
    unsigned int e = binned[i];
    int j = (int)(e & 255u);
    int s = (int)(e >> 8);
    int p = atomicAdd(&cur[j], 1);
    srcs[base + p] = s;
  }
  if (b == 0 && t == 0) offs[N_NODES] = TOTE;
}

// ====== W prep: fp32 W[k][n] -> frag-ready bf16 hi/lo streams; block16: WlT[c][k] ======
__global__ __launch_bounds__(256) void k_wprep(const float* __restrict__ W1, const float* __restrict__ W2,
                                               const float* __restrict__ Wl,
                                               unsigned short* __restrict__ B1hi, unsigned short* __restrict__ B1lo,
                                               unsigned short* __restrict__ B2hi, unsigned short* __restrict__ B2lo,
                                               float* __restrict__ WlT) {
  int b = blockIdx.x;                       // 0..16
  int t = threadIdx.x;
  if (b == 16) {
    for (int i = t; i < 1280; i += 256) {
      int c = i >> 7, k = i & 127;
      WlT[i] = Wl[k * 10 + c];
    }
    return;
  }
  const float* W = (b < 8) ? W1 : W2;
  unsigned short* Bh = (b < 8) ? B1hi : B2hi;
  unsigned short* Bl = (b < 8) ? B1lo : B2lo;
  int ntile = b & 7;
  int kq = t >> 6, lane = t & 63;
  int q = lane >> 4, m = lane & 15;
  int n = ntile * 16 + m;
  union { unsigned short us[8]; uint4 u4; } hi, lo;
#pragma unroll
  for (int j = 0; j < 8; ++j) {
    int k = kq * 32 + q * 8 + j;
    float w = W[(size_t)k * 128 + n];
    unsigned int u = __float_as_uint(w);
    hi.us[j] = (unsigned short)(u >> 16);                 // truncation hi
    float res = w - __uint_as_float(u & 0xffff0000u);     // exact residual
    lo.us[j] = f2bf(res);
  }
  size_t fo = ((size_t)(ntile * 4 + kq) * 64 + lane) * 8;
  *reinterpret_cast<uint4*>(Bh + fo) = hi.u4;
  *reinterpret_cast<uint4*>(Bl + fo) = lo.u4;
}

// ====== MFMA GEMM, 64-row tiles (occupancy-tuned) + fused alpha dots + block max; bf16 C out ======
// wave w owns cols w*32..w*32+31 (2 n-tiles), all 64 rows (4 m-tiles). acc 4x2 -> ~32 VGPR.
template <bool SPLIT>
__global__ __launch_bounds__(256) void k_gemm_mfma(const void* __restrict__ Aptr,
                                                   const unsigned short* __restrict__ Bhi,
                                                   const unsigned short* __restrict__ Blo,
                                                   unsigned short* __restrict__ Cb,
                                                   const float* __restrict__ avS, const float* __restrict__ avD,
                                                   float* __restrict__ aS, float* __restrict__ aD,
                                                   float* __restrict__ slotS, float* __restrict__ slotD) {
  __shared__ unsigned short sC[64 * 136];
  __shared__ float redS[64 * 4], redD[64 * 4];
  __shared__ float mS[64], mD[64];
  int t = threadIdx.x;
  int w = t >> 6, lane = t & 63;
  int q = lane >> 4, m = lane & 15;
  int rbase = blockIdx.x * 64;

  floatx4 acc[4][2];
#pragma unroll
  for (int mt = 0; mt < 4; ++mt)
#pragma unroll
    for (int nt = 0; nt < 2; ++nt) acc[mt][nt] = (floatx4){0.f, 0.f, 0.f, 0.f};

#pragma unroll
  for (int k0 = 0; k0 < 4; ++k0) {
    bf16x8 Bh[2], Bl[2], Ah[4], Al[4];
#pragma unroll
    for (int nt = 0; nt < 2; ++nt) {
      int ntg = w * 2 + nt;
      size_t fo = ((size_t)(ntg * 4 + k0) * 64 + lane) * 8;
      Bh[nt] = *reinterpret_cast<const bf16x8*>(Bhi + fo);
      Bl[nt] = *reinterpret_cast<const bf16x8*>(Blo + fo);
    }
#pragma unroll
    for (int mt = 0; mt < 4; ++mt) {
      int row = rbase + mt * 16 + m;
      row = min(row, N_NODES - 1);
      if constexpr (SPLIT) {
        const float* ap = (const float*)Aptr + (size_t)row * 128 + k0 * 32 + q * 8;
        float4 v0 = *reinterpret_cast<const float4*>(ap);
        float4 v1 = *reinterpret_cast<const float4*>(ap + 4);
        float av[8] = {v0.x, v0.y, v0.z, v0.w, v1.x, v1.y, v1.z, v1.w};
        union { unsigned short us[8]; bf16x8 v; } uh, ul;
#pragma unroll
        for (int j = 0; j < 8; ++j) {
          unsigned int u = __float_as_uint(av[j]);
          uh.us[j] = (unsigned short)(u >> 16);
          float res = av[j] - __uint_as_float(u & 0xffff0000u);
          ul.us[j] = f2bf(res);
        }
        Ah[mt] = uh.v; Al[mt] = ul.v;
      } else {
        const unsigned short* ap = (const unsigned short*)Aptr + (size_t)row * 128 + k0 * 32 + q * 8;
        Ah[mt] = *reinterpret_cast<const bf16x8*>(ap);
      }
    }
#pragma unroll
    for (int mt = 0; mt < 4; ++mt)
#pragma unroll
      for (int nt = 0; nt < 2; ++nt) {
        acc[mt][nt] = __builtin_amdgcn_mfma_f32_16x16x32_bf16(Ah[mt], Bh[nt], acc[mt][nt], 0, 0, 0);
        acc[mt][nt] = __builtin_amdgcn_mfma_f32_16x16x32_bf16(Ah[mt], Bl[nt], acc[mt][nt], 0, 0, 0);
        if constexpr (SPLIT)
          acc[mt][nt] = __builtin_amdgcn_mfma_f32_16x16x32_bf16(Al[mt], Bh[nt], acc[mt][nt], 0, 0, 0);
      }
  }

  // ---- fused alpha dots: partials over this wave's 32 cols, shfl-reduce across m ----
  float avs[2], avd[2];
#pragma unroll
  for (int nt = 0; nt < 2; ++nt) {
    int c = w * 32 + nt * 16 + m;
    avs[nt] = avS[c];
    avd[nt] = avD[c];
  }
#pragma unroll
  for (int mt = 0; mt < 4; ++mt)
#pragma unroll
    for (int r = 0; r < 4; ++r) {
      float ps = acc[mt][0][r] * avs[0] + acc[mt][1][r] * avs[1];
      float pd = acc[mt][0][r] * avd[0] + acc[mt][1][r] * avd[1];
      ps += __shfl_xor(ps, 1); pd += __shfl_xor(pd, 1);
      ps += __shfl_xor(ps, 2); pd += __shfl_xor(pd, 2);
      ps += __shfl_xor(ps, 4); pd += __shfl_xor(pd, 4);
      ps += __shfl_xor(ps, 8); pd += __shfl_xor(pd, 8);
      if (m == 0) {
        int rl = mt * 16 + q * 4 + r;
        redS[rl * 4 + w] = ps;
        redD[rl * 4 + w] = pd;
      }
    }

  // ---- C -> LDS (bf16) ----
#pragma unroll
  for (int mt = 0; mt < 4; ++mt)
#pragma unroll
    for (int nt = 0; nt < 2; ++nt)
#pragma unroll
      for (int r = 0; r < 4; ++r) {
        int rl = mt * 16 + q * 4 + r;
        int cl = w * 32 + nt * 16 + m;
        sC[rl * 136 + cl] = f2bf(acc[mt][nt][r]);
      }
  __syncthreads();

  // ---- coalesced C store (64 rows x 128 cols) ----
#pragma unroll
  for (int i = 0; i < 4; ++i) {
    int idx = i * 256 + t;
    int rl = idx >> 4, kk = idx & 15;
    int gr = rbase + rl;
    if (gr < N_NODES)
      *reinterpret_cast<uint4*>(Cb + (size_t)gr * 128 + kk * 8) =
          *reinterpret_cast<const uint4*>(sC + rl * 136 + kk * 8);
  }

  // ---- alpha combine + block max ----
  if (t < 64) {
    int gr = rbase + t;
    bool ok = gr < N_NODES;
    float ps = redS[t * 4] + redS[t * 4 + 1] + redS[t * 4 + 2] + redS[t * 4 + 3];
    float pd = redD[t * 4] + redD[t * 4 + 1] + redD[t * 4 + 2] + redD[t * 4 + 3];
    if (ok) { aS[gr] = ps; aD[gr] = pd; }
    mS[t] = ok ? ps : -1e30f;
    mD[t] = ok ? pd : -1e30f;
  }
  __syncthreads();
#pragma unroll
  for (int off = 32; off > 0; off >>= 1) {
    if (t < off) { mS[t] = fmaxf(mS[t], mS[t + off]); mD[t] = fmaxf(mD[t], mD[t + off]); }
    __syncthreads();
  }
  if (t == 0) { slotS[blockIdx.x] = mS[0]; slotD[blockIdx.x] = mD[0]; }
}

__global__ __launch_bounds__(256) void k_gmax(const float* __restrict__ slotS,
                                              const float* __restrict__ slotD,
                                              int n, float* __restrict__ gMh) {
  __shared__ float sS[256], sD[256];
  int t = threadIdx.x;
  float ms = -1e30f, md = -1e30f;
  for (int i = t; i < n; i += 256) { ms = fmaxf(ms, slotS[i]); md = fmaxf(md, slotD[i]); }
  sS[t] = ms; sD[t] = md;
  __syncthreads();
#pragma unroll
  for (int off = 128; off > 0; off >>= 1) {
    if (t < off) { sS[t] = fmaxf(sS[t], sS[t + off]); sD[t] = fmaxf(sD[t], sD[t + off]); }
    __syncthreads();
  }
  if (t == 0) {
    float M = sS[0] + sD[0];
    gMh[0] = (M > 0.f) ? M : NEG * M;
  }
}

// ============ single-pass softmax + aggregation (16 lanes/dst, identity order, 4-deep) ============
#define FMA8(E, R)                                     \
  do {                                                 \
    acc[0] += (E) * bf_lo((R).x); acc[1] += (E) * bf_hi((R).x); \
    acc[2] += (E) * bf_lo((R).y); acc[3] += (E) * bf_hi((R).y); \
    acc[4] += (E) * bf_lo((R).z); acc[5] += (E) * bf_hi((R).z); \
    acc[6] += (E) * bf_lo((R).w); acc[7] += (E) * bf_hi((R).w); \
  } while (0)

template <bool FUSECLS>
__global__ __launch_bounds__(256) void k_aggregate(const unsigned short* __restrict__ hb,
                                                   const float* __restrict__ aS,
                                                   const float* __restrict__ aD,
                                                   const int* __restrict__ offs,
                                                   const int* __restrict__ srcs,
                                                   const float* __restrict__ bias,
                                                   const float* __restrict__ gMh,
                                                   unsigned short* __restrict__ outb,
                                                   const float* __restrict__ WlT,
                                                   const float* __restrict__ bl,
                                                   float* __restrict__ out) {
  __shared__ float2 pairs[16 * 17];
  int t = threadIdx.x;
  int g = t >> 4;
  int l = t & 15;
  int dst = blockIdx.x * 16 + g;   // N_NODES == 16*6250 exactly
  float Mh = gMh[0];
  int beg = offs[dst], end = offs[dst + 1];
  float adn = aD[dst];
  float denom = 0.f;
  float acc[8];
#pragma unroll
  for (int k = 0; k < 8; ++k) acc[k] = 0.f;
  const int pbase = g * 17;

  for (int chunk = beg; chunk < end; chunk += 16) {
    int i = chunk + l;
    float ex = 0.f; int s = 0;
    if (i < end) {
      s = srcs[i];
      float e = aS[s] + adn;
      e = (e > 0.f) ? e : NEG * e;
      ex = __expf(e - Mh);   // Mh >= e always
    }
    denom += ex;
    pairs[pbase + l] = make_float2(ex, __int_as_float(s));
    // same-wave LDS RAW: DS ops in order per wave; no barrier needed
    int cnt = min(16, end - chunk);
    int j = 0;
    for (; j + 4 <= cnt; j += 4) {
      float2 p0 = pairs[pbase + j + 0];
      float2 p1 = pairs[pbase + j + 1];
      float2 p2 = pairs[pbase + j + 2];
      float2 p3 = pairs[pbase + j + 3];
      uint4 r0 = *reinterpret_cast<const uint4*>(hb + (size_t)__float_as_int(p0.y) * 128 + l * 8);
      uint4 r1 = *reinterpret_cast<const uint4*>(hb + (size_t)__float_as_int(p1.y) * 128 + l * 8);
      uint4 r2 = *reinterpret_cast<const uint4*>(hb + (size_t)__float_as_int(p2.y) * 128 + l * 8);
      uint4 r3 = *reinterpret_cast<const uint4*>(hb + (size_t)__float_as_int(p3.y) * 128 + l * 8);
      FMA8(p0.x, r0);
      FMA8(p1.x, r1);
      FMA8(p2.x, r2);
      FMA8(p3.x, r3);
    }
    for (; j < cnt; ++j) {
      float2 pp = pairs[pbase + j];
      uint4 r = *reinterpret_cast<const uint4*>(hb + (size_t)__float_as_int(pp.y) * 128 + l * 8);
      FMA8(pp.x, r);
    }
  }
  denom += __shfl_xor(denom, 1);
  denom += __shfl_xor(denom, 2);
  denom += __shfl_xor(denom, 4);
  denom += __shfl_xor(denom, 8);
  float inv = 1.f / (denom + 1e-16f);
  float4 b0 = *reinterpret_cast<const float4*>(bias + l * 8);
  float4 b1 = *reinterpret_cast<const float4*>(bias + l * 8 + 4);
  float o0 = fmaxf(acc[0] * inv + b0.x, 0.f), o1 = fmaxf(acc[1] * inv + b0.y, 0.f);
  float o2 = fmaxf(acc[2] * inv + b0.z, 0.f), o3 = fmaxf(acc[3] * inv + b0.w, 0.f);
  float o4 = fmaxf(acc[4] * inv + b1.x, 0.f), o5 = fmaxf(acc[5] * inv + b1.y, 0.f);
  float o6 = fmaxf(acc[6] * inv + b1.z, 0.f), o7 = fmaxf(acc[7] * inv + b1.w, 0.f);

  if constexpr (!FUSECLS) {
    union { unsigned short us[8]; uint4 u4; } oo;
    oo.us[0] = f2bf(o0); oo.us[1] = f2bf(o1); oo.us[2] = f2bf(o2); oo.us[3] = f2bf(o3);
    oo.us[4] = f2bf(o4); oo.us[5] = f2bf(o5); oo.us[6] = f2bf(o6); oo.us[7] = f2bf(o7);
    *reinterpret_cast<uint4*>(outb + (size_t)dst * 128 + l * 8) = oo.u4;
  } else {
    // classifier: p[c] = sum_k h[k] * Wl[k][c]; lane holds k = l*8..l*8+7
    float p[10];
#pragma unroll
    for (int c = 0; c < 10; ++c) {
      const float4* wp = reinterpret_cast<const float4*>(WlT + c * 128 + l * 8);
      float4 w0 = wp[0], w1 = wp[1];
      p[c] = o0 * w0.x + o1 * w0.y + o2 * w0.z + o3 * w0.w
           + o4 * w1.x + o5 * w1.y + o6 * w1.z + o7 * w1.w;
    }
#pragma unroll
    for (int c = 0; c < 10; ++c) {
      p[c] += __shfl_xor(p[c], 1);
      p[c] += __shfl_xor(p[c], 2);
      p[c] += __shfl_xor(p[c], 4);
      p[c] += __shfl_xor(p[c], 8);
    }
    if (l == 0) {
      float* orow = out + (size_t)dst * 10;
      float2 bb0 = *reinterpret_cast<const float2*>(bl + 0);
      float2 bb1 = *reinterpret_cast<const float2*>(bl + 2);
      float2 bb2 = *reinterpret_cast<const float2*>(bl + 4);
      float2 bb3 = *reinterpret_cast<const float2*>(bl + 6);
      float2 bb4 = *reinterpret_cast<const float2*>(bl + 8);
      *reinterpret_cast<float2*>(orow + 0) = make_float2(p[0] + bb0.x, p[1] + bb0.y);
      *reinterpret_cast<float2*>(orow + 2) = make_float2(p[2] + bb1.x, p[3] + bb1.y);
      *reinterpret_cast<float2*>(orow + 4) = make_float2(p[4] + bb2.x, p[5] + bb2.y);
      *reinterpret_cast<float2*>(orow + 6) = make_float2(p[6] + bb3.x, p[7] + bb3.y);
      *reinterpret_cast<float2*>(orow + 8) = make_float2(p[8] + bb4.x, p[9] + bb4.y);
    }
  }
}

// ====================== launch ======================
extern "C" void kernel_launch(void* const* d_in, const int* in_sizes, int n_in,
                              void* d_out, int out_size, void* d_ws, size_t ws_size,
                              hipStream_t stream) {
  const float* x   = (const float*)d_in[0];
  const int*   ei  = (const int*)d_in[1];
  const float* W1  = (const float*)d_in[3];
  const float* as1 = (const float*)d_in[4];
  const float* ad1 = (const float*)d_in[5];
  const float* b1  = (const float*)d_in[6];
  const float* W2  = (const float*)d_in[7];
  const float* as2 = (const float*)d_in[8];
  const float* ad2 = (const float*)d_in[9];
  const float* b2  = (const float*)d_in[10];
  const float* Wl  = (const float*)d_in[11];
  const float* bl  = (const float*)d_in[12];
  float* out = (float*)d_out;

  char* p = (char*)d_ws;
  unsigned short* hb   = (unsigned short*)p; p += (size_t)N_NODES * 128 * sizeof(unsigned short);
  unsigned short* hagg = (unsigned short*)p; p += (size_t)N_NODES * 128 * sizeof(unsigned short);
  float* aS    = (float*)p; p += (size_t)N_NODES * sizeof(float);
  float* aD    = (float*)p; p += (size_t)N_NODES * sizeof(float);
  int* offs    = (int*)p;   p += (size_t)(N_NODES + 4) * sizeof(int);
  int* srcs    = (int*)p;   p += (size_t)TOTE * sizeof(int);
  int* bucketCnt = (int*)p; p += (size_t)NB * 16 * sizeof(int);
  int* binOffs   = (int*)p; p += (size_t)(NB + 4) * sizeof(int);
  int* binCursor = (int*)p; p += (size_t)NB * 16 * sizeof(int);
  float* slotS = (float*)p; p += 2048 * sizeof(float);   // 1563 gemm blocks
  float* slotD = (float*)p; p += 2048 * sizeof(float);
  float* gMh = (float*)p;   p += 4 * sizeof(float);
  unsigned short* B1hi = (unsigned short*)p; p += 128 * 128 * sizeof(unsigned short);
  unsigned short* B1lo = (unsigned short*)p; p += 128 * 128 * sizeof(unsigned short);
  unsigned short* B2hi = (unsigned short*)p; p += 128 * 128 * sizeof(unsigned short);
  unsigned short* B2lo = (unsigned short*)p; p += 128 * 128 * sizeof(unsigned short);
  float* WlT = (float*)p;   p += 1280 * sizeof(float);
  unsigned int* binned = (unsigned int*)hagg;  // alias: binned dead before hagg is written

  int binBlocks = (N_EDGES + 4095) / 4096;  // 391

  k_wprep<<<17, 256, 0, stream>>>(W1, W2, Wl, B1hi, B1lo, B2hi, B2lo, WlT);
  k_zero_bcnt<<<1, 256, 0, stream>>>(bucketCnt);
  k_bucket_hist<<<binBlocks, 256, 0, stream>>>(ei, bucketCnt);
  k_bin_scan<<<1, 512, 0, stream>>>(bucketCnt, binOffs, binCursor);
  k_binA<<<binBlocks, 256, 0, stream>>>(ei, binCursor, binned);
  k_binB<<<NB, 256, 0, stream>>>(binned, binOffs, offs, srcs);

  int gemmBlocks = (N_NODES + 63) / 64;     // 1563
  int aggBlocks  = N_NODES / 16;            // 6250

  // layer 1
  k_gemm_mfma<true><<<gemmBlocks, 256, 0, stream>>>(x, B1hi, B1lo, hb, as1, ad1, aS, aD, slotS, slotD);
  k_gmax<<<1, 256, 0, stream>>>(slotS, slotD, gemmBlocks, gMh);
  k_aggregate<false><<<aggBlocks, 256, 0, stream>>>(hb, aS, aD, offs, srcs, b1, gMh,
                                                    hagg, nullptr, nullptr, nullptr);
  // layer 2
  k_gemm_mfma<false><<<gemmBlocks, 256, 0, stream>>>(hagg, B2hi, B2lo, hb, as2, ad2, aS, aD, slotS, slotD);
  k_gmax<<<1, 256, 0, stream>>>(slotS, slotD, gemmBlocks, gMh);
  k_aggregate<true><<<aggBlocks, 256, 0, stream>>>(hb, aS, aD, offs, srcs, b2, gMh,
                                                   nullptr, WlT, bl, out);
}

// Round 10
// 364.902 us; speedup vs baseline: 1.0705x; 1.0684x over previous
//
#include <hip/hip_runtime.h>

#define N_NODES 100000
#define N_EDGES 1600000
#define TOTE    (N_EDGES + N_NODES)
#define NEG     0.2f
#define NB      ((N_NODES + 255) >> 8)   // 391 buckets of 256 nodes
#define BCAP    5120                     // bucket capacity (mean 4096 + 16 sigma)

typedef __attribute__((ext_vector_type(8))) short bf16x8;
typedef __attribute__((ext_vector_type(4))) float floatx4;

// bf16 helpers (RTNE)
__device__ __forceinline__ unsigned short f2bf(float f) {
  unsigned int u = __float_as_uint(f);
  u += 0x7fffu + ((u >> 16) & 1u);
  return (unsigned short)(u >> 16);
}
__device__ __forceinline__ float bf_lo(unsigned int r) { return __uint_as_float(r << 16); }
__device__ __forceinline__ float bf_hi(unsigned int r) { return __uint_as_float(r & 0xffff0000u); }

// ====== W prep (blocks 0..15) + bucket counter zeroing (block 16) ======
__global__ __launch_bounds__(256) void k_wprep(const float* __restrict__ W1, const float* __restrict__ W2,
                                               unsigned short* __restrict__ B1hi, unsigned short* __restrict__ B1lo,
                                               unsigned short* __restrict__ B2hi, unsigned short* __restrict__ B2lo,
                                               int* __restrict__ bucketCnt) {
  int b = blockIdx.x;                       // 0..16
  int t = threadIdx.x;
  if (b == 16) {
    for (int i = t; i < NB * 16; i += 256) bucketCnt[i] = 0;
    return;
  }
  const float* W = (b < 8) ? W1 : W2;
  unsigned short* Bh = (b < 8) ? B1hi : B2hi;
  unsigned short* Bl = (b < 8) ? B1lo : B2lo;
  int ntile = b & 7;
  int kq = t >> 6, lane = t & 63;
  int q = lane >> 4, m = lane & 15;
  int n = ntile * 16 + m;
  union { unsigned short us[8]; uint4 u4; } hi, lo;
#pragma unroll
  for (int j = 0; j < 8; ++j) {
    int k = kq * 32 + q * 8 + j;
    float w = W[(size_t)k * 128 + n];
    unsigned int u = __float_as_uint(w);
    hi.us[j] = (unsigned short)(u >> 16);                 // truncation hi
    float res = w - __uint_as_float(u & 0xffff0000u);     // exact residual
    lo.us[j] = f2bf(res);
  }
  size_t fo = ((size_t)(ntile * 4 + kq) * 64 + lane) * 8;
  *reinterpret_cast<uint4*>(Bh + fo) = hi.u4;
  *reinterpret_cast<uint4*>(Bl + fo) = lo.u4;
}

// ====== pass A: partition edges into fixed-capacity buckets, packed (src<<8)|(dst&255) ======
__global__ __launch_bounds__(256) void k_binA(const int* __restrict__ ei, int* __restrict__ bucketCnt,
                                              unsigned int* __restrict__ binned) {
  __shared__ int hist[NB];
  __shared__ int cur[NB];
  int t = threadIdx.x;
  for (int b = t; b < NB; b += 256) hist[b] = 0;
  __syncthreads();
  unsigned int pk[16]; int bk[16];
#pragma unroll
  for (int j = 0; j < 16; ++j) {
    int idx = blockIdx.x * 4096 + j * 256 + t;
    if (idx < N_EDGES) {
      int s = ei[idx], d = ei[N_EDGES + idx];
      bk[j] = d >> 8;
      pk[j] = ((unsigned int)s << 8) | (unsigned int)(d & 255);
      atomicAdd(&hist[bk[j]], 1);
    } else bk[j] = -1;
  }
  __syncthreads();
  for (int b = t; b < NB; b += 256) {
    int h = hist[b];
    if (h) cur[b] = b * BCAP + atomicAdd(&bucketCnt[b * 16], h);
  }
  __syncthreads();
#pragma unroll
  for (int j = 0; j < 16; ++j) {
    if (bk[j] >= 0) {
      int pos = atomicAdd(&cur[bk[j]], 1);
      binned[pos] = pk[j];
    }
  }
}

// exclusive scan of final bucket counts -> binOffs
__global__ __launch_bounds__(512) void k_bin_scan(const int* __restrict__ bucketCnt,
                                                  int* __restrict__ binOffs) {
  __shared__ int sc[512];
  int t = threadIdx.x;
  int v = (t < NB) ? bucketCnt[t * 16] : 0;
  sc[t] = v; __syncthreads();
  for (int off = 1; off < 512; off <<= 1) {
    int x = (t >= off) ? sc[t - off] : 0;
    __syncthreads();
    sc[t] += x;
    __syncthreads();
  }
  int excl = sc[t] - v;
  if (t <= NB) binOffs[t] = excl;
}

// pass B: per-bucket exact CSR (offs + srcs)
__global__ __launch_bounds__(256) void k_binB(const unsigned int* __restrict__ binned,
                                              const int* __restrict__ binOffs,
                                              int* __restrict__ offs, int* __restrict__ srcs) {
  __shared__ int cnt[256];
  __shared__ int sc[256];
  __shared__ int cur[256];
  int b = blockIdx.x;
  int t = threadIdx.x;
  int node0 = b << 8;
  int nNodes = min(256, N_NODES - node0);
  int cntE = binOffs[b + 1] - binOffs[b];
  int e0 = b * BCAP, e1 = e0 + cntE;
  int base = binOffs[b] + node0;   // prior real edges + prior self-loops

  cnt[t] = 0; __syncthreads();
  for (int i = e0 + t; i < e1; i += 256) atomicAdd(&cnt[binned[i] & 255u], 1);
  __syncthreads();

  int v = (t < nNodes) ? cnt[t] + 1 : 0;   // +1 self-loop
  sc[t] = v; __syncthreads();
  for (int off = 1; off < 256; off <<= 1) {
    int x = (t >= off) ? sc[t - off] : 0;
    __syncthreads();
    sc[t] += x;
    __syncthreads();
  }
  int excl = sc[t] - v;
  if (t < nNodes) {
    offs[node0 + t] = base + excl;
    srcs[base + excl] = node0 + t;   // self-loop first
  }
  cur[t] = excl + 1;
  __syncthreads();

  for (int i = e0 + t; i < e1; i += 256) {
    unsigned int e = binned[i];
    int j = (int)(e & 255u);
    int s = (int)(e >> 8);
    int p = atomicAdd(&cur[j], 1);
    srcs[base + p] = s;
  }
  if (b == 0 && t == 0) offs[N_NODES] = TOTE;
}

// ====== MFMA GEMM, 64-row tiles + fused alpha dots + block max; bf16 C out ======
template <bool SPLIT>
__global__ __launch_bounds__(256) void k_gemm_mfma(const void* __restrict__ Aptr,
                                                   const unsigned short* __restrict__ Bhi,
                                                   const unsigned short* __restrict__ Blo,
                                                   unsigned short* __restrict__ Cb,
                                                   const float* __restrict__ avS, const float* __restrict__ avD,
                                                   float* __restrict__ aS, float* __restrict__ aD,
                                                   float* __restrict__ slotS, float* __restrict__ slotD) {
  __shared__ unsigned short sC[64 * 136];
  __shared__ float redS[64 * 4], redD[64 * 4];
  __shared__ float mS[64], mD[64];
  int t = threadIdx.x;
  int w = t >> 6, lane = t & 63;
  int q = lane >> 4, m = lane & 15;
  int rbase = blockIdx.x * 64;

  floatx4 acc[4][2];
#pragma unroll
  for (int mt = 0; mt < 4; ++mt)
#pragma unroll
    for (int nt = 0; nt < 2; ++nt) acc[mt][nt] = (floatx4){0.f, 0.f, 0.f, 0.f};

#pragma unroll
  for (int k0 = 0; k0 < 4; ++k0) {
    bf16x8 Bh[2], Bl[2], Ah[4], Al[4];
#pragma unroll
    for (int nt = 0; nt < 2; ++nt) {
      int ntg = w * 2 + nt;
      size_t fo = ((size_t)(ntg * 4 + k0) * 64 + lane) * 8;
      Bh[nt] = *reinterpret_cast<const bf16x8*>(Bhi + fo);
      Bl[nt] = *reinterpret_cast<const bf16x8*>(Blo + fo);
    }
#pragma unroll
    for (int mt = 0; mt < 4; ++mt) {
      int row = rbase + mt * 16 + m;
      row = min(row, N_NODES - 1);
      if constexpr (SPLIT) {
        const float* ap = (const float*)Aptr + (size_t)row * 128 + k0 * 32 + q * 8;
        float4 v0 = *reinterpret_cast<const float4*>(ap);
        float4 v1 = *reinterpret_cast<const float4*>(ap + 4);
        float av[8] = {v0.x, v0.y, v0.z, v0.w, v1.x, v1.y, v1.z, v1.w};
        union { unsigned short us[8]; bf16x8 v; } uh, ul;
#pragma unroll
        for (int j = 0; j < 8; ++j) {
          unsigned int u = __float_as_uint(av[j]);
          uh.us[j] = (unsigned short)(u >> 16);
          float res = av[j] - __uint_as_float(u & 0xffff0000u);
          ul.us[j] = f2bf(res);
        }
        Ah[mt] = uh.v; Al[mt] = ul.v;
      } else {
        const unsigned short* ap = (const unsigned short*)Aptr + (size_t)row * 128 + k0 * 32 + q * 8;
        Ah[mt] = *reinterpret_cast<const bf16x8*>(ap);
      }
    }
#pragma unroll
    for (int mt = 0; mt < 4; ++mt)
#pragma unroll
      for (int nt = 0; nt < 2; ++nt) {
        acc[mt][nt] = __builtin_amdgcn_mfma_f32_16x16x32_bf16(Ah[mt], Bh[nt], acc[mt][nt], 0, 0, 0);
        acc[mt][nt] = __builtin_amdgcn_mfma_f32_16x16x32_bf16(Ah[mt], Bl[nt], acc[mt][nt], 0, 0, 0);
        if constexpr (SPLIT)
          acc[mt][nt] = __builtin_amdgcn_mfma_f32_16x16x32_bf16(Al[mt], Bh[nt], acc[mt][nt], 0, 0, 0);
      }
  }

  // ---- fused alpha dots ----
  float avs[2], avd[2];
#pragma unroll
  for (int nt = 0; nt < 2; ++nt) {
    int c = w * 32 + nt * 16 + m;
    avs[nt] = avS[c];
    avd[nt] = avD[c];
  }
#pragma unroll
  for (int mt = 0; mt < 4; ++mt)
#pragma unroll
    for (int r = 0; r < 4; ++r) {
      float ps = acc[mt][0][r] * avs[0] + acc[mt][1][r] * avs[1];
      float pd = acc[mt][0][r] * avd[0] + acc[mt][1][r] * avd[1];
      ps += __shfl_xor(ps, 1); pd += __shfl_xor(pd, 1);
      ps += __shfl_xor(ps, 2); pd += __shfl_xor(pd, 2);
      ps += __shfl_xor(ps, 4); pd += __shfl_xor(pd, 4);
      ps += __shfl_xor(ps, 8); pd += __shfl_xor(pd, 8);
      if (m == 0) {
        int rl = mt * 16 + q * 4 + r;
        redS[rl * 4 + w] = ps;
        redD[rl * 4 + w] = pd;
      }
    }

  // ---- C -> LDS (bf16) ----
#pragma unroll
  for (int mt = 0; mt < 4; ++mt)
#pragma unroll
    for (int nt = 0; nt < 2; ++nt)
#pragma unroll
      for (int r = 0; r < 4; ++r) {
        int rl = mt * 16 + q * 4 + r;
        int cl = w * 32 + nt * 16 + m;
        sC[rl * 136 + cl] = f2bf(acc[mt][nt][r]);
      }
  __syncthreads();

  // ---- coalesced C store ----
#pragma unroll
  for (int i = 0; i < 4; ++i) {
    int idx = i * 256 + t;
    int rl = idx >> 4, kk = idx & 15;
    int gr = rbase + rl;
    if (gr < N_NODES)
      *reinterpret_cast<uint4*>(Cb + (size_t)gr * 128 + kk * 8) =
          *reinterpret_cast<const uint4*>(sC + rl * 136 + kk * 8);
  }

  // ---- alpha combine + block max ----
  if (t < 64) {
    int gr = rbase + t;
    bool ok = gr < N_NODES;
    float ps = redS[t * 4] + redS[t * 4 + 1] + redS[t * 4 + 2] + redS[t * 4 + 3];
    float pd = redD[t * 4] + redD[t * 4 + 1] + redD[t * 4 + 2] + redD[t * 4 + 3];
    if (ok) { aS[gr] = ps; aD[gr] = pd; }
    mS[t] = ok ? ps : -1e30f;
    mD[t] = ok ? pd : -1e30f;
  }
  __syncthreads();
#pragma unroll
  for (int off = 32; off > 0; off >>= 1) {
    if (t < off) { mS[t] = fmaxf(mS[t], mS[t + off]); mD[t] = fmaxf(mD[t], mD[t + off]); }
    __syncthreads();
  }
  if (t == 0) { slotS[blockIdx.x] = mS[0]; slotD[blockIdx.x] = mD[0]; }
}

__global__ __launch_bounds__(256) void k_gmax(const float* __restrict__ slotS,
                                              const float* __restrict__ slotD,
                                              int n, float* __restrict__ gMh) {
  __shared__ float sS[256], sD[256];
  int t = threadIdx.x;
  float ms = -1e30f, md = -1e30f;
  for (int i = t; i < n; i += 256) { ms = fmaxf(ms, slotS[i]); md = fmaxf(md, slotD[i]); }
  sS[t] = ms; sD[t] = md;
  __syncthreads();
#pragma unroll
  for (int off = 128; off > 0; off >>= 1) {
    if (t < off) { sS[t] = fmaxf(sS[t], sS[t + off]); sD[t] = fmaxf(sD[t], sD[t + off]); }
    __syncthreads();
  }
  if (t == 0) {
    float M = sS[0] + sD[0];
    gMh[0] = (M > 0.f) ? M : NEG * M;
  }
}

// ============ single-pass softmax + aggregation (round-7 lean form: VGPR ~36, 62% occ) ============
#define FMA8(E, R)                                     \
  do {                                                 \
    acc[0] += (E) * bf_lo((R).x); acc[1] += (E) * bf_hi((R).x); \
    acc[2] += (E) * bf_lo((R).y); acc[3] += (E) * bf_hi((R).y); \
    acc[4] += (E) * bf_lo((R).z); acc[5] += (E) * bf_hi((R).z); \
    acc[6] += (E) * bf_lo((R).w); acc[7] += (E) * bf_hi((R).w); \
  } while (0)

__global__ __launch_bounds__(256) void k_aggregate(const unsigned short* __restrict__ hb,
                                                   const float* __restrict__ aS,
                                                   const float* __restrict__ aD,
                                                   const int* __restrict__ offs,
                                                   const int* __restrict__ srcs,
                                                   const float* __restrict__ bias,
                                                   const float* __restrict__ gMh,
                                                   unsigned short* __restrict__ outb) {
  __shared__ float2 pairs[16 * 17];
  int t = threadIdx.x;
  int g = t >> 4;
  int l = t & 15;
  int dst = blockIdx.x * 16 + g;   // N_NODES == 16*6250 exactly
  float Mh = gMh[0];
  int beg = offs[dst], end = offs[dst + 1];
  float adn = aD[dst];
  float denom = 0.f;
  float acc[8];
#pragma unroll
  for (int k = 0; k < 8; ++k) acc[k] = 0.f;
  const int pbase = g * 17;

  for (int chunk = beg; chunk < end; chunk += 16) {
    int i = chunk + l;
    float ex = 0.f; int s = 0;
    if (i < end) {
      s = srcs[i];
      float e = aS[s] + adn;
      e = (e > 0.f) ? e : NEG * e;
      ex = __expf(e - Mh);   // Mh >= e always
    }
    denom += ex;
    pairs[pbase + l] = make_float2(ex, __int_as_float(s));
    // same-wave LDS RAW: DS ops in order per wave; no barrier needed
    int cnt = min(16, end - chunk);
    int j = 0;
    for (; j + 4 <= cnt; j += 4) {
      float2 p0 = pairs[pbase + j + 0];
      float2 p1 = pairs[pbase + j + 1];
      float2 p2 = pairs[pbase + j + 2];
      float2 p3 = pairs[pbase + j + 3];
      uint4 r0 = *reinterpret_cast<const uint4*>(hb + (size_t)__float_as_int(p0.y) * 128 + l * 8);
      uint4 r1 = *reinterpret_cast<const uint4*>(hb + (size_t)__float_as_int(p1.y) * 128 + l * 8);
      uint4 r2 = *reinterpret_cast<const uint4*>(hb + (size_t)__float_as_int(p2.y) * 128 + l * 8);
      uint4 r3 = *reinterpret_cast<const uint4*>(hb + (size_t)__float_as_int(p3.y) * 128 + l * 8);
      FMA8(p0.x, r0);
      FMA8(p1.x, r1);
      FMA8(p2.x, r2);
      FMA8(p3.x, r3);
    }
    for (; j < cnt; ++j) {
      float2 pp = pairs[pbase + j];
      uint4 r = *reinterpret_cast<const uint4*>(hb + (size_t)__float_as_int(pp.y) * 128 + l * 8);
      FMA8(pp.x, r);
    }
  }
  denom += __shfl_xor(denom, 1);
  denom += __shfl_xor(denom, 2);
  denom += __shfl_xor(denom, 4);
  denom += __shfl_xor(denom, 8);
  float inv = 1.f / (denom + 1e-16f);
  float4 b0 = *reinterpret_cast<const float4*>(bias + l * 8);
  float4 b1 = *reinterpret_cast<const float4*>(bias + l * 8 + 4);
  float o0 = fmaxf(acc[0] * inv + b0.x, 0.f), o1 = fmaxf(acc[1] * inv + b0.y, 0.f);
  float o2 = fmaxf(acc[2] * inv + b0.z, 0.f), o3 = fmaxf(acc[3] * inv + b0.w, 0.f);
  float o4 = fmaxf(acc[4] * inv + b1.x, 0.f), o5 = fmaxf(acc[5] * inv + b1.y, 0.f);
  float o6 = fmaxf(acc[6] * inv + b1.z, 0.f), o7 = fmaxf(acc[7] * inv + b1.w, 0.f);
  union { unsigned short us[8]; uint4 u4; } oo;
  oo.us[0] = f2bf(o0); oo.us[1] = f2bf(o1); oo.us[2] = f2bf(o2); oo.us[3] = f2bf(o3);
  oo.us[4] = f2bf(o4); oo.us[5] = f2bf(o5); oo.us[6] = f2bf(o6); oo.us[7] = f2bf(o7);
  *reinterpret_cast<uint4*>(outb + (size_t)dst * 128 + l * 8) = oo.u4;
}

// ====================== final classifier [N,128]@[128,10]+b (4 lanes/node, bf16 in) ==============
#define UNPK(V, B)                                     \
  do {                                                 \
    h[(B)+0] = bf_lo((V).x); h[(B)+1] = bf_hi((V).x);  \
    h[(B)+2] = bf_lo((V).y); h[(B)+3] = bf_hi((V).y);  \
    h[(B)+4] = bf_lo((V).z); h[(B)+5] = bf_hi((V).z);  \
    h[(B)+6] = bf_lo((V).w); h[(B)+7] = bf_hi((V).w);  \
  } while (0)

__global__ __launch_bounds__(256) void k_linear(const unsigned short* __restrict__ hb,
                                                const float* __restrict__ Wl,
                                                const float* __restrict__ bl,
                                                float* __restrict__ out) {
  // transposed W: sWt[c][j*36 + i] = Wl[(j*32+i)*10 + c]; j-chunk stride 36 -> banks {0,4,8,12}
  __shared__ float sWt[10 * 144];
  __shared__ float sbl[10];
  int t = threadIdx.x;
  if (t < 128) {
    int jj = t >> 5, ii = t & 31;
#pragma unroll
    for (int c = 0; c < 10; ++c) sWt[c * 144 + jj * 36 + ii] = Wl[t * 10 + c];
  }
  if (t < 10) sbl[t] = bl[t];
  __syncthreads();
  int node = blockIdx.x * 64 + (t >> 2);
  int j = t & 3;
  if (node >= N_NODES) return;
  const unsigned short* hrow = hb + (size_t)node * 128 + j * 32;
  uint4 v0 = *reinterpret_cast<const uint4*>(hrow);
  uint4 v1 = *reinterpret_cast<const uint4*>(hrow + 8);
  uint4 v2 = *reinterpret_cast<const uint4*>(hrow + 16);
  uint4 v3 = *reinterpret_cast<const uint4*>(hrow + 24);
  float h[32];
  UNPK(v0, 0); UNPK(v1, 8); UNPK(v2, 16); UNPK(v3, 24);
  float p[10];
#pragma unroll
  for (int c = 0; c < 10; ++c) {
    const float4* wp = reinterpret_cast<const float4*>(&sWt[c * 144 + j * 36]);
    float s = 0.f;
#pragma unroll
    for (int qq = 0; qq < 8; ++qq) {
      float4 wv = wp[qq];
      s += h[qq * 4 + 0] * wv.x + h[qq * 4 + 1] * wv.y + h[qq * 4 + 2] * wv.z + h[qq * 4 + 3] * wv.w;
    }
    p[c] = s;
  }
#pragma unroll
  for (int c = 0; c < 10; ++c) {
    p[c] += __shfl_xor(p[c], 1);
    p[c] += __shfl_xor(p[c], 2);
  }
  if (j == 0) {
    float* orow = out + (size_t)node * 10;
    *reinterpret_cast<float2*>(orow + 0) = make_float2(p[0] + sbl[0], p[1] + sbl[1]);
    *reinterpret_cast<float2*>(orow + 2) = make_float2(p[2] + sbl[2], p[3] + sbl[3]);
    *reinterpret_cast<float2*>(orow + 4) = make_float2(p[4] + sbl[4], p[5] + sbl[5]);
    *reinterpret_cast<float2*>(orow + 6) = make_float2(p[6] + sbl[6], p[7] + sbl[7]);
    *reinterpret_cast<float2*>(orow + 8) = make_float2(p[8] + sbl[8], p[9] + sbl[9]);
  }
}

// ====================== launch ======================
extern "C" void kernel_launch(void* const* d_in, const int* in_sizes, int n_in,
                              void* d_out, int out_size, void* d_ws, size_t ws_size,
                              hipStream_t stream) {
  const float* x   = (const float*)d_in[0];
  const int*   ei  = (const int*)d_in[1];
  const float* W1  = (const float*)d_in[3];
  const float* as1 = (const float*)d_in[4];
  const float* ad1 = (const float*)d_in[5];
  const float* b1  = (const float*)d_in[6];
  const float* W2  = (const float*)d_in[7];
  const float* as2 = (const float*)d_in[8];
  const float* ad2 = (const float*)d_in[9];
  const float* b2  = (const float*)d_in[10];
  const float* Wl  = (const float*)d_in[11];
  const float* bl  = (const float*)d_in[12];
  float* out = (float*)d_out;

  char* p = (char*)d_ws;
  unsigned short* hb   = (unsigned short*)p; p += (size_t)N_NODES * 128 * sizeof(unsigned short);
  unsigned short* hagg = (unsigned short*)p; p += (size_t)N_NODES * 128 * sizeof(unsigned short);
  float* aS    = (float*)p; p += (size_t)N_NODES * sizeof(float);
  float* aD    = (float*)p; p += (size_t)N_NODES * sizeof(float);
  int* offs    = (int*)p;   p += (size_t)(N_NODES + 4) * sizeof(int);
  int* srcs    = (int*)p;   p += (size_t)TOTE * sizeof(int);
  int* bucketCnt = (int*)p; p += (size_t)NB * 16 * sizeof(int);
  int* binOffs   = (int*)p; p += (size_t)(NB + 4) * sizeof(int);
  float* slotS = (float*)p; p += 2048 * sizeof(float);   // 1563 gemm blocks
  float* slotD = (float*)p; p += 2048 * sizeof(float);
  float* gMh = (float*)p;   p += 4 * sizeof(float);
  unsigned short* B1hi = (unsigned short*)p; p += 128 * 128 * sizeof(unsigned short);
  unsigned short* B1lo = (unsigned short*)p; p += 128 * 128 * sizeof(unsigned short);
  unsigned short* B2hi = (unsigned short*)p; p += 128 * 128 * sizeof(unsigned short);
  unsigned short* B2lo = (unsigned short*)p; p += 128 * 128 * sizeof(unsigned short);
  // binned bucket array (NB*BCAP uints = 8 MB) aliases hagg+hb tail region: use hagg (25.6MB), dead until layer-1 agg
  unsigned int* binned = (unsigned int*)hagg;

  int binBlocks = (N_EDGES + 4095) / 4096;  // 391

  k_wprep<<<17, 256, 0, stream>>>(W1, W2, B1hi, B1lo, B2hi, B2lo, bucketCnt);
  k_binA<<<binBlocks, 256, 0, stream>>>(ei, bucketCnt, binned);
  k_bin_scan<<<1, 512, 0, stream>>>(bucketCnt, binOffs);
  k_binB<<<NB, 256, 0, stream>>>(binned, binOffs, offs, srcs);

  int gemmBlocks = (N_NODES + 63) / 64;     // 1563
  int aggBlocks  = N_NODES / 16;            // 6250
  int linBlocks  = (N_NODES + 63) / 64;     // 1563

  // layer 1
  k_gemm_mfma<true><<<gemmBlocks, 256, 0, stream>>>(x, B1hi, B1lo, hb, as1, ad1, aS, aD, slotS, slotD);
  k_gmax<<<1, 256, 0, stream>>>(slotS, slotD, gemmBlocks, gMh);
  k_aggregate<<<aggBlocks, 256, 0, stream>>>(hb, aS, aD, offs, srcs, b1, gMh, hagg);
  // layer 2
  k_gemm_mfma<false><<<gemmBlocks, 256, 0, stream>>>(hagg, B2hi, B2lo, hb, as2, ad2, aS, aD, slotS, slotD);
  k_gmax<<<1, 256, 0, stream>>>(slotS, slotD, gemmBlocks, gMh);
  k_aggregate<<<aggBlocks, 256, 0, stream>>>(hb, aS, aD, offs, srcs, b2, gMh, hagg);
  // classifier
  k_linear<<<linBlocks, 256, 0, stream>>>(hagg, Wl, bl, out);
}